// Round 3
// baseline (229.511 us; speedup 1.0000x reference)
//
#include <hip/hip_runtime.h>

#define N_SAMPLES 131072
#define N_FEAT    512
#define N_PAIRS   (N_SAMPLES / 2)
#define N_KER     29
#define MAX_NB    1024
#define PAIR_F    (2 * N_FEAT)   // floats per pair (two adjacent rows)

// 8 float4 = 32 VGPRs of loaded data per pipeline stage.
struct Batch {
  float4 x0, x1, xp0, xp1, y0, y1, yp0, yp1;
};

__device__ __forceinline__ void load_batch(const float* __restrict__ Xs,
                                           const float* __restrict__ Xt,
                                           int p, int o0, Batch& b) {
  // p is wave-uniform (readfirstlane'd upstream) -> base stays scalar,
  // only o0 (lane*4) is per-lane.
  const float* x = Xs + (size_t)p * PAIR_F;
  const float* y = Xt + (size_t)p * PAIR_F;
  b.x0  = *reinterpret_cast<const float4*>(x + o0);
  b.x1  = *reinterpret_cast<const float4*>(x + o0 + 256);
  b.xp0 = *reinterpret_cast<const float4*>(x + o0 + N_FEAT);
  b.xp1 = *reinterpret_cast<const float4*>(x + o0 + N_FEAT + 256);
  b.y0  = *reinterpret_cast<const float4*>(y + o0);
  b.y1  = *reinterpret_cast<const float4*>(y + o0 + 256);
  b.yp0 = *reinterpret_cast<const float4*>(y + o0 + N_FEAT);
  b.yp1 = *reinterpret_cast<const float4*>(y + o0 + N_FEAT + 256);
}

__device__ __forceinline__ void compute_pair(const Batch& b, double c, int lane,
                                             double& acc) {
  double d0 = 0.0, d1 = 0.0, d2 = 0.0, d3 = 0.0;

#define MMD_ACC(A, AP, B, BP)                                   \
  {                                                             \
    const double ax  = (double)(A);                             \
    const double axp = (double)(AP);                            \
    const double ay  = (double)(B);                             \
    const double ayp = (double)(BP);                            \
    double t;                                                   \
    t = ax - axp; d0 = fma(t, t, d0);                           \
    t = ay - ayp; d1 = fma(t, t, d1);                           \
    t = ax - ayp; d2 = fma(t, t, d2);                           \
    t = axp - ay; d3 = fma(t, t, d3);                           \
  }
  MMD_ACC(b.x0.x, b.xp0.x, b.y0.x, b.yp0.x)
  MMD_ACC(b.x0.y, b.xp0.y, b.y0.y, b.yp0.y)
  MMD_ACC(b.x0.z, b.xp0.z, b.y0.z, b.yp0.z)
  MMD_ACC(b.x0.w, b.xp0.w, b.y0.w, b.yp0.w)
  MMD_ACC(b.x1.x, b.xp1.x, b.y1.x, b.yp1.x)
  MMD_ACC(b.x1.y, b.xp1.y, b.y1.y, b.yp1.y)
  MMD_ACC(b.x1.z, b.xp1.z, b.y1.z, b.yp1.z)
  MMD_ACC(b.x1.w, b.xp1.w, b.y1.w, b.yp1.w)
#undef MMD_ACC

  // butterfly reduce across 64 lanes (result broadcast to all lanes)
#pragma unroll
  for (int s = 32; s > 0; s >>= 1) {
    d0 += __shfl_xor(d0, s);
    d1 += __shfl_xor(d1, s);
    d2 += __shfl_xor(d2, s);
    d3 += __shfl_xor(d3, s);
  }

  if (lane < N_KER) {
    acc += exp(-d0 * c) + exp(-d1 * c) - exp(-d2 * c) - exp(-d3 * c);
  }
}

// Kernel 1: per-wave contiguous pair chunk with depth-4 load pipeline;
// per-block partials (32 padded doubles) into d_ws.
__global__ __launch_bounds__(256, 3) void mmd_partial(
    const float* __restrict__ Xs, const float* __restrict__ Xt,
    double* __restrict__ ws, int nwaves) {
  const int tid  = threadIdx.x;
  const int lane = tid & 63;
  const int wib  = tid >> 6;
  const int gw   = __builtin_amdgcn_readfirstlane(blockIdx.x * 4 + wib);
  const int cpw  = N_PAIRS / nwaves;           // uniform (pow-2 grid), >= 16
  const int o0   = lane * 4;

  // inv_two_gamma_sq[g] = 2^(6 - 0.5*g), exact
  const double c = exp2(6.0 - 0.5 * (double)lane);
  double acc = 0.0;

  const int p0 = gw * cpw;                     // contiguous chunk [p0, p0+cpw)
  Batch A, B, C, D;
  load_batch(Xs, Xt, p0 + 0, o0, A);
  load_batch(Xs, Xt, p0 + 1, o0, B);
  load_batch(Xs, Xt, p0 + 2, o0, C);
  load_batch(Xs, Xt, p0 + 3, o0, D);

  int p = p0 + 4;
  for (int rep = 0; rep < cpw / 4 - 1; ++rep) {
    compute_pair(A, c, lane, acc); load_batch(Xs, Xt, p + 0, o0, A);
    compute_pair(B, c, lane, acc); load_batch(Xs, Xt, p + 1, o0, B);
    compute_pair(C, c, lane, acc); load_batch(Xs, Xt, p + 2, o0, C);
    compute_pair(D, c, lane, acc); load_batch(Xs, Xt, p + 3, o0, D);
    p += 4;
  }
  compute_pair(A, c, lane, acc);
  compute_pair(B, c, lane, acc);
  compute_pair(C, c, lane, acc);
  compute_pair(D, c, lane, acc);

  // block reduction: 4 waves -> 32 padded doubles
  __shared__ double sacc[4][32];
  if (lane < 32) sacc[wib][lane] = (lane < N_KER) ? acc : 0.0;
  __syncthreads();
  if (tid < 32) {
    const double s = sacc[0][tid] + sacc[1][tid] + sacc[2][tid] + sacc[3][tid];
    ws[(size_t)blockIdx.x * 32 + tid] = s;
  }
}

// Kernel 2: deterministic reduction over block partials; fold betas; mean.
__global__ __launch_bounds__(1024) void mmd_final(
    const double* __restrict__ ws, const float* __restrict__ betas,
    float* __restrict__ out, int nb) {
  const int tid = threadIdx.x;
  double acc = 0.0;
  const int total = nb * 32;
  for (int i = tid; i < total; i += 1024) {
    const int g = i & 31;
    if (g < N_KER) acc += (double)betas[g] * ws[i];
  }
  __shared__ double s[1024];
  s[tid] = acc;
  __syncthreads();
  for (int ofs = 512; ofs > 0; ofs >>= 1) {
    if (tid < ofs) s[tid] += s[tid + ofs];
    __syncthreads();
  }
  if (tid == 0) out[0] = (float)(s[0] / (double)N_PAIRS);
}

extern "C" void kernel_launch(void* const* d_in, const int* in_sizes, int n_in,
                              void* d_out, int out_size, void* d_ws, size_t ws_size,
                              hipStream_t stream) {
  const float* Xs    = (const float*)d_in[0];
  const float* Xt    = (const float*)d_in[1];
  const float* betas = (const float*)d_in[2];
  float*  out = (float*)d_out;
  double* ws  = (double*)d_ws;

  // Largest power-of-two block count that fits ws (32 doubles per block),
  // capped at MAX_NB. Pow-2 keeps cpw = N_PAIRS / (4*nb) integral.
  size_t nb_fit = ws_size / (32 * sizeof(double));
  int nb = 1;
  while ((size_t)(nb * 2) <= nb_fit && nb * 2 <= MAX_NB) nb *= 2;

  mmd_partial<<<nb, 256, 0, stream>>>(Xs, Xt, ws, nb * 4);
  mmd_final<<<1, 1024, 0, stream>>>(ws, betas, out, nb);
}

// Round 4
// 107.655 us; speedup vs baseline: 2.1319x; 2.1319x over previous
//
#include <hip/hip_runtime.h>

#define N_SAMPLES 131072
#define N_FEAT    512
#define N_PAIRS   (N_SAMPLES / 2)
#define N_KER     29
#define PAIR_F    (2 * N_FEAT)          // floats per pair (two adjacent rows)

#define NB_MAIN   1024                  // tuned path: 1024 blocks x 4 waves
#define NW_MAIN   (NB_MAIN * 4)         // 4096 waves
#define CPW_MAIN  (N_PAIRS / NW_MAIN)   // 16 pairs/wave (16 % 3 == 1, needed below)

// 8 float4 = 32 VGPRs of loaded data per pipeline stage.
struct Batch {
  float4 x0, x1, xp0, xp1, y0, y1, yp0, yp1;
};

__device__ __forceinline__ void load_batch(const float* __restrict__ Xs,
                                           const float* __restrict__ Xt,
                                           int p, int o0, Batch& b) {
  const float* x = Xs + (size_t)p * PAIR_F;
  const float* y = Xt + (size_t)p * PAIR_F;
  b.x0  = *reinterpret_cast<const float4*>(x + o0);
  b.x1  = *reinterpret_cast<const float4*>(x + o0 + 256);
  b.xp0 = *reinterpret_cast<const float4*>(x + o0 + N_FEAT);
  b.xp1 = *reinterpret_cast<const float4*>(x + o0 + N_FEAT + 256);
  b.y0  = *reinterpret_cast<const float4*>(y + o0);
  b.y1  = *reinterpret_cast<const float4*>(y + o0 + 256);
  b.yp0 = *reinterpret_cast<const float4*>(y + o0 + N_FEAT);
  b.yp1 = *reinterpret_cast<const float4*>(y + o0 + N_FEAT + 256);
}

__device__ __forceinline__ void compute_pair(const Batch& b, double c, int lane,
                                             double& acc) {
  double d0 = 0.0, d1 = 0.0, d2 = 0.0, d3 = 0.0;

#define MMD_ACC(A, AP, B, BP)                                   \
  {                                                             \
    const double ax  = (double)(A);                             \
    const double axp = (double)(AP);                            \
    const double ay  = (double)(B);                             \
    const double ayp = (double)(BP);                            \
    double t;                                                   \
    t = ax - axp; d0 = fma(t, t, d0);                           \
    t = ay - ayp; d1 = fma(t, t, d1);                           \
    t = ax - ayp; d2 = fma(t, t, d2);                           \
    t = axp - ay; d3 = fma(t, t, d3);                           \
  }
  MMD_ACC(b.x0.x, b.xp0.x, b.y0.x, b.yp0.x)
  MMD_ACC(b.x0.y, b.xp0.y, b.y0.y, b.yp0.y)
  MMD_ACC(b.x0.z, b.xp0.z, b.y0.z, b.yp0.z)
  MMD_ACC(b.x0.w, b.xp0.w, b.y0.w, b.yp0.w)
  MMD_ACC(b.x1.x, b.xp1.x, b.y1.x, b.yp1.x)
  MMD_ACC(b.x1.y, b.xp1.y, b.y1.y, b.yp1.y)
  MMD_ACC(b.x1.z, b.xp1.z, b.y1.z, b.yp1.z)
  MMD_ACC(b.x1.w, b.xp1.w, b.y1.w, b.yp1.w)
#undef MMD_ACC

  // butterfly reduce across 64 lanes (result broadcast to all lanes)
#pragma unroll
  for (int s = 32; s > 0; s >>= 1) {
    d0 += __shfl_xor(d0, s);
    d1 += __shfl_xor(d1, s);
    d2 += __shfl_xor(d2, s);
    d3 += __shfl_xor(d3, s);
  }

  if (lane < N_KER) {
    acc += exp(-d0 * c) + exp(-d1 * c) - exp(-d2 * c) - exp(-d3 * c);
  }
}

__device__ __forceinline__ void block_reduce_store(double acc, int lane, int wib,
                                                   int tid, double* __restrict__ ws) {
  __shared__ double sacc[4][32];
  if (lane < 32) sacc[wib][lane] = (lane < N_KER) ? acc : 0.0;
  __syncthreads();
  if (tid < 32) {
    const double s = sacc[0][tid] + sacc[1][tid] + sacc[2][tid] + sacc[3][tid];
    ws[(size_t)blockIdx.x * 32 + tid] = s;
  }
}

// Tuned path: nb=1024 fixed, 16 pairs/wave, strided round-robin sweep
// (R2's proven access pattern), depth-3 register pipeline (2 batches in
// flight under each compute). No min-occupancy clamp: ~140 VGPR must NOT
// spill (R3 lesson: launch_bounds(256,3) -> 84 VGPR + 444 MB scratch).
__global__ __launch_bounds__(256) void mmd_partial_main(
    const float* __restrict__ Xs, const float* __restrict__ Xt,
    double* __restrict__ ws) {
  const int tid  = threadIdx.x;
  const int lane = tid & 63;
  const int wib  = tid >> 6;
  const int gw   = blockIdx.x * 4 + wib;
  const int o0   = lane * 4;

  const double c = exp2(6.0 - 0.5 * (double)lane);  // 1/(2*gamma_g^2) exact
  double acc = 0.0;

  int pl = gw;                         // next pair index to load
  Batch A, B, C;
  load_batch(Xs, Xt, pl, o0, A); pl += NW_MAIN;
  load_batch(Xs, Xt, pl, o0, B); pl += NW_MAIN;

  // 16 pairs total: 4 main iterations consume 12, epilogue consumes 4.
#pragma unroll 1
  for (int it = 0; it < (CPW_MAIN - 4) / 3; ++it) {
    load_batch(Xs, Xt, pl, o0, C); pl += NW_MAIN;
    compute_pair(A, c, lane, acc);
    load_batch(Xs, Xt, pl, o0, A); pl += NW_MAIN;
    compute_pair(B, c, lane, acc);
    load_batch(Xs, Xt, pl, o0, B); pl += NW_MAIN;
    compute_pair(C, c, lane, acc);
  }
  load_batch(Xs, Xt, pl, o0, C); pl += NW_MAIN;
  compute_pair(A, c, lane, acc);
  load_batch(Xs, Xt, pl, o0, A);       // 16th (last) pair
  compute_pair(B, c, lane, acc);
  compute_pair(C, c, lane, acc);
  compute_pair(A, c, lane, acc);

  block_reduce_store(acc, lane, wib, tid, ws);
}

// Fallback (ws too small for 1024 blocks): R2's generic depth-2 pipeline.
__global__ __launch_bounds__(256) void mmd_partial_fb(
    const float* __restrict__ Xs, const float* __restrict__ Xt,
    double* __restrict__ ws, int nwaves) {
  const int tid  = threadIdx.x;
  const int lane = tid & 63;
  const int wib  = tid >> 6;
  const int gw   = blockIdx.x * 4 + wib;
  const int o0   = lane * 4;

  const double c = exp2(6.0 - 0.5 * (double)lane);
  double acc = 0.0;

  int p = gw;
  if (p < N_PAIRS) {
    Batch A, B;
    load_batch(Xs, Xt, p, o0, A);
    int pn = p + nwaves;
    bool pendingA = true;
    while (pn < N_PAIRS) {
      load_batch(Xs, Xt, pn, o0, B);
      compute_pair(A, c, lane, acc);
      pn += nwaves;
      if (pn < N_PAIRS) {
        load_batch(Xs, Xt, pn, o0, A);
        compute_pair(B, c, lane, acc);
        pn += nwaves;
      } else {
        compute_pair(B, c, lane, acc);
        pendingA = false;
        break;
      }
    }
    if (pendingA) compute_pair(A, c, lane, acc);
  }

  block_reduce_store(acc, lane, wib, tid, ws);
}

// Final deterministic reduction; fold betas; mean.
__global__ __launch_bounds__(1024) void mmd_final(
    const double* __restrict__ ws, const float* __restrict__ betas,
    float* __restrict__ out, int nb) {
  const int tid = threadIdx.x;
  double acc = 0.0;
  const int total = nb * 32;
  for (int i = tid; i < total; i += 1024) {
    const int g = i & 31;
    if (g < N_KER) acc += (double)betas[g] * ws[i];
  }
  __shared__ double s[1024];
  s[tid] = acc;
  __syncthreads();
  for (int ofs = 512; ofs > 0; ofs >>= 1) {
    if (tid < ofs) s[tid] += s[tid + ofs];
    __syncthreads();
  }
  if (tid == 0) out[0] = (float)(s[0] / (double)N_PAIRS);
}

extern "C" void kernel_launch(void* const* d_in, const int* in_sizes, int n_in,
                              void* d_out, int out_size, void* d_ws, size_t ws_size,
                              hipStream_t stream) {
  const float* Xs    = (const float*)d_in[0];
  const float* Xt    = (const float*)d_in[1];
  const float* betas = (const float*)d_in[2];
  float*  out = (float*)d_out;
  double* ws  = (double*)d_ws;

  if (ws_size >= (size_t)NB_MAIN * 32 * sizeof(double)) {
    mmd_partial_main<<<NB_MAIN, 256, 0, stream>>>(Xs, Xt, ws);
    mmd_final<<<1, 1024, 0, stream>>>(ws, betas, out, NB_MAIN);
  } else {
    size_t nb_fit = ws_size / (32 * sizeof(double));
    int nb = 1;
    while ((size_t)(nb * 2) <= nb_fit && nb * 2 <= NB_MAIN) nb *= 2;
    mmd_partial_fb<<<nb, 256, 0, stream>>>(Xs, Xt, ws, nb * 4);
    mmd_final<<<1, 1024, 0, stream>>>(ws, betas, out, nb);
  }
}